// Round 9
// baseline (57.770 us; speedup 1.0000x reference)
//
#include <hip/hip_runtime.h>

typedef unsigned short u16;
typedef __bf16 bf16x8 __attribute__((ext_vector_type(8)));
typedef float f32x16 __attribute__((ext_vector_type(16)));

#define B_   16
#define H_   56
#define W_   56
#define C_   128
#define OH_  54
#define OW_  54
#define NF_  256
#define KF_  1152           // C_*9
#define M_   46656          // B_*OH_*OW_
#define NNZ_ 58982

#define XB_ELEMS (B_*H_*W_*C_)       // 6422528
#define WT_ELEMS (36*4*256*8)        // 294912 (pre-tiled [kt][p][col][8])

__device__ __forceinline__ u16 f2bf(float f) {
    unsigned u = __float_as_uint(f);
    u += 0x7FFFu + ((u >> 16) & 1u);
    return (u16)(u >> 16);
}

__device__ __forceinline__ void gload16(const void* g, void* l) {
    __builtin_amdgcn_global_load_lds(
        (const __attribute__((address_space(1))) unsigned int*)g,
        (__attribute__((address_space(3))) unsigned int*)l,
        16, 0, 0);
}

// ---- kernel 1: x f32 -> bf16 (8/thread) + fused zeroing of wt ----
__global__ __launch_bounds__(256) void cvt_x_kernel(const float* __restrict__ x,
                                                    u16* __restrict__ xb,
                                                    u16* __restrict__ wt) {
    if (blockIdx.x < 144) {
        uint4 z = {0u, 0u, 0u, 0u};
        ((uint4*)wt)[blockIdx.x * 256 + threadIdx.x] = z;
    }
    int i = (blockIdx.x * 256 + threadIdx.x) * 8;
    float4 v0 = *(const float4*)(x + i);
    float4 v1 = *(const float4*)(x + i + 4);
    union { u16 u[8]; uint4 v; } r;
    r.u[0] = f2bf(v0.x); r.u[1] = f2bf(v0.y); r.u[2] = f2bf(v0.z); r.u[3] = f2bf(v0.w);
    r.u[4] = f2bf(v1.x); r.u[5] = f2bf(v1.y); r.u[6] = f2bf(v1.z); r.u[7] = f2bf(v1.w);
    *(uint4*)(xb + i) = r.v;
}

// ---- kernel 2: scatter sparse values into PRE-TILED W: [kt][p][col][8] ----
__global__ __launch_bounds__(256) void scatter_kernel(const float* __restrict__ kv,
                                                      const int* __restrict__ idx,
                                                      u16* __restrict__ wt) {
    int t = blockIdx.x * 256 + threadIdx.x;
    if (t >= NNZ_) return;
    int k   = idx[2*t];      // row in [0,1152)
    int col = idx[2*t + 1];  // col in [0,256)
    int kt = k >> 5, ks = (k >> 3) & 3, e = k & 7;
    wt[(kt * 4 + ks) * 2048 + col * 8 + e] = f2bf(kv[t]);
}

// ---- kernel 3: 8-wave high-TLP implicit GEMM ----
// grid 729 (BM=64), 512 threads = 8 waves, wave tile 32x64 (wr=w>>2, wc=w&3)
// via mfma_32x32x16_bf16. acc 32 VGPR + B-dbuf 32 -> ~110 VGPR => 4 waves/SIMD
// (16 waves/CU, 2 blocks resident). A: LDS dbuf 2x4KB, XOR-slot swizzle
// (uniform bank residues); staged by waves 0-3 (1 gload_lds/thread).
// B: global->VGPR dwordx4 from pre-tiled wt, 4/thread/tile, dbuf regsets.
// Counted vmcnt(5)/(4) per wave role — never drains to 0 mid-loop.
__global__ __launch_bounds__(512, 4) void spconv_gemm(const u16* __restrict__ xb,
                                                      const u16* __restrict__ wt,
                                                      const float* __restrict__ bias,
                                                      float* __restrict__ out) {
    __shared__ __align__(16) u16 As[2][64 * 32];   // 2 x 4 KB, [row][4 slots][8]

    const int t   = threadIdx.x;    // 0..511
    const int l   = t & 63;
    const int w   = t >> 6;         // wave 0..7
    const int l31 = l & 31;
    const int hi  = l >> 5;
    const int wr  = w >> 2;         // row half: rows wr*32..+31
    const int wc  = w & 3;          // col quarter: cols wc*64..+63

    // bijective XCD swizzle (nwg=729 -> m204 formula)
    const int nwg = gridDim.x;
    const int q = nwg >> 3, r = nwg & 7;
    const int xcd = blockIdx.x & 7, inner = blockIdx.x >> 3;
    const int wg = (xcd < r ? xcd * (q + 1) : r * (q + 1) + (xcd - r) * q) + inner;
    const int m0 = wg * 64;

    // ---- A staging setup (threads 0..255): cell t = (row=t>>2, sd=t&3),
    // source chunk = sd ^ f(row), f(row) = (row&3)^((row>>2)&3).
    const int arow = (t & 255) >> 2;
    const int kco  = (((t & 3) ^ (arow & 3) ^ ((arow >> 2) & 3))) * 8;
    const u16* a_base;
    {
        int mg  = m0 + arow;
        int bb  = mg / (OH_ * OW_);
        int rem = mg % (OH_ * OW_);
        int ii  = rem / OW_;
        int jj  = rem % OW_;
        a_base = xb + ((bb * H_ + ii) * W_ + jj) * C_;
    }

    // ---- A read offsets (elems): row = wr*32+l31, slot = (kp*2+hi)^fr
    const int fr = (l31 & 3) ^ ((l31 >> 2) & 3);
    int aoff0 = (wr * 32 + l31) * 32 + ((0 * 2 + hi) ^ fr) * 8;   // kp=0
    int aoff1 = (wr * 32 + l31) * 32 + ((1 * 2 + hi) ^ fr) * 8;   // kp=1

    // ---- B bases (bytes): [kt][p][col][8]; p = kp*2+hi, col = wc*64+cb*32+l31
    const char* wtb = (const char*)wt;
    const char* b0 = wtb + hi * 4096 + (wc * 64 + l31) * 16;   // kp=0
    const char* b1 = b0 + 8192;                                 // kp=1

    f32x16 acc[2];
    acc[0] = (f32x16)0.f; acc[1] = (f32x16)0.f;

    bf16x8 bS0[4], bS1[4];   // dbuf regsets, index = kp*2 + cb

#define LOADB(dst, base, imm) \
    asm volatile("global_load_dwordx4 %0, %1, off offset:" imm \
                 : "=v"(dst) : "v"(base) : "memory")

#define ISSUE_A(kn, bi) do {                                                \
    if (t < 256) {                                                          \
        int g_  = (kn) >> 2;                                                \
        int di_ = (g_ * 11) >> 5;                                           \
        int dj_ = g_ - 3 * di_;                                             \
        int aoff_ = (di_ * W_ + dj_) * C_ + ((kn) & 3) * 32 + kco;          \
        gload16(a_base + aoff_, &As[bi][t * 8]);                            \
    }                                                                       \
} while (0)

#define ISSUE_B(bset) do {                                                  \
    LOADB(bset[0], b0, "0");   LOADB(bset[1], b0, "512");                   \
    LOADB(bset[2], b1, "0");   LOADB(bset[3], b1, "512");                   \
    b0 += 16384; b1 += 16384;                                               \
} while (0)

#define COMPUTE(bi, bset) do {                                              \
    bf16x8 af0_ = *(const bf16x8*)(&As[bi][aoff0]);                         \
    acc[0] = __builtin_amdgcn_mfma_f32_32x32x16_bf16(af0_, bset[0], acc[0], 0, 0, 0); \
    acc[1] = __builtin_amdgcn_mfma_f32_32x32x16_bf16(af0_, bset[1], acc[1], 0, 0, 0); \
    bf16x8 af1_ = *(const bf16x8*)(&As[bi][aoff1]);                         \
    acc[0] = __builtin_amdgcn_mfma_f32_32x32x16_bf16(af1_, bset[2], acc[0], 0, 0, 0); \
    acc[1] = __builtin_amdgcn_mfma_f32_32x32x16_bf16(af1_, bset[3], acc[1], 0, 0, 0); \
} while (0)

// per-role counted waits: A-staging waves have 5 vmem/tile, others 4
#define WAITVM(nb, na) do {                                                 \
    if (t < 256) { asm volatile("s_waitcnt vmcnt(" #nb ")" ::: "memory"); } \
    else         { asm volatile("s_waitcnt vmcnt(" #na ")" ::: "memory"); } \
} while (0)
#define WAITLG0() asm volatile("s_waitcnt lgkmcnt(0)" ::: "memory")
#define BAR() do { __builtin_amdgcn_s_barrier();                            \
                   asm volatile("" ::: "memory"); } while (0)

    // prologue: tiles 0,1 in flight
    ISSUE_A(0, 0); ISSUE_B(bS0);
    ISSUE_A(1, 1); ISSUE_B(bS1);

    // main loop: 17 pairs, compute tiles 0..33, issue 2..35
#pragma unroll
    for (int k2 = 0; k2 < 17; ++k2) {
        WAITVM(5, 4); BAR();            // tile 2k2 landed; 2k2+1 in flight
        COMPUTE(0, bS0);
        WAITLG0(); BAR();               // all waves done reading As[0]
        ISSUE_A(2 * k2 + 2, 0); ISSUE_B(bS0);
        WAITVM(5, 4); BAR();
        COMPUTE(1, bS1);
        WAITLG0(); BAR();
        ISSUE_A(2 * k2 + 3, 1); ISSUE_B(bS1);
    }
    // tail: tiles 34, 35
    WAITVM(5, 4); BAR(); COMPUTE(0, bS0);
    WAITVM(0, 0); BAR(); COMPUTE(1, bS1);

#undef LOADB
#undef ISSUE_A
#undef ISSUE_B
#undef COMPUTE
#undef WAITVM
#undef WAITLG0
#undef BAR

    // epilogue: 32x32 C/D layout col=lane&31, row=(reg&3)+8*(reg>>2)+4*(lane>>5)
#pragma unroll
    for (int cb = 0; cb < 2; ++cb) {
        int col  = wc * 64 + cb * 32 + l31;
        float bv = bias[col];
#pragma unroll
        for (int rg = 0; rg < 16; ++rg) {
            int row = m0 + wr * 32 + (rg & 3) + 8 * (rg >> 2) + 4 * hi;
            out[row * NF_ + col] = fmaxf(acc[cb][rg] + bv, 0.f);
        }
    }
}

extern "C" void kernel_launch(void* const* d_in, const int* in_sizes, int n_in,
                              void* d_out, int out_size, void* d_ws, size_t ws_size,
                              hipStream_t stream) {
    const float* x    = (const float*)d_in[0];
    const float* kv   = (const float*)d_in[1];
    const float* bias = (const float*)d_in[2];
    const int*   idx  = (const int*)d_in[3];
    float* out = (float*)d_out;

    u16* xb  = (u16*)d_ws;
    u16* wtp = (u16*)((char*)d_ws + (size_t)XB_ELEMS * 2);

    cvt_x_kernel<<<XB_ELEMS / (256 * 8), 256, 0, stream>>>(x, xb, wtp);
    scatter_kernel<<<(NNZ_ + 255) / 256, 256, 0, stream>>>(kv, idx, wtp);
    spconv_gemm<<<M_ / 64, 512, 0, stream>>>(xb, wtp, bias, out);
}

// Round 10
// 42.628 us; speedup vs baseline: 1.3552x; 1.3552x over previous
//
#include <hip/hip_runtime.h>

typedef unsigned short u16;
typedef __bf16 bf16x8 __attribute__((ext_vector_type(8)));
typedef float f32x4 __attribute__((ext_vector_type(4)));

#define B_   16
#define H_   56
#define W_   56
#define C_   128
#define OH_  54
#define OW_  54
#define NF_  256
#define KF_  1152           // C_*9
#define M_   46656          // B_*OH_*OW_
#define NNZ_ 58982

#define XB_ELEMS (B_*H_*W_*C_)       // 6422528
#define WT_ELEMS (36*4*256*8)        // 294912 (pre-tiled [kt][ks][col][8])

__device__ __forceinline__ u16 f2bf(float f) {
    unsigned u = __float_as_uint(f);
    u += 0x7FFFu + ((u >> 16) & 1u);
    return (u16)(u >> 16);
}

__device__ __forceinline__ void gload16(const void* g, void* l) {
    __builtin_amdgcn_global_load_lds(
        (const __attribute__((address_space(1))) unsigned int*)g,
        (__attribute__((address_space(3))) unsigned int*)l,
        16, 0, 0);
}

// ---- kernel 1: x f32 -> bf16 (8/thread) + fused zeroing of wt ----
__global__ __launch_bounds__(256) void cvt_x_kernel(const float* __restrict__ x,
                                                    u16* __restrict__ xb,
                                                    u16* __restrict__ wt) {
    if (blockIdx.x < 144) {
        uint4 z = {0u, 0u, 0u, 0u};
        ((uint4*)wt)[blockIdx.x * 256 + threadIdx.x] = z;
    }
    int i = (blockIdx.x * 256 + threadIdx.x) * 8;
    float4 v0 = *(const float4*)(x + i);
    float4 v1 = *(const float4*)(x + i + 4);
    union { u16 u[8]; uint4 v; } r;
    r.u[0] = f2bf(v0.x); r.u[1] = f2bf(v0.y); r.u[2] = f2bf(v0.z); r.u[3] = f2bf(v0.w);
    r.u[4] = f2bf(v1.x); r.u[5] = f2bf(v1.y); r.u[6] = f2bf(v1.z); r.u[7] = f2bf(v1.w);
    *(uint4*)(xb + i) = r.v;
}

// ---- kernel 2: scatter sparse values into PRE-TILED W: [kt][ks][col][8] ----
__global__ __launch_bounds__(256) void scatter_kernel(const float* __restrict__ kv,
                                                      const int* __restrict__ idx,
                                                      u16* __restrict__ wt) {
    int t = blockIdx.x * 256 + threadIdx.x;
    if (t >= NNZ_) return;
    int k   = idx[2*t];      // row in [0,1152)
    int col = idx[2*t + 1];  // col in [0,256)
    int kt = k >> 5, ks = (k >> 3) & 3, e = k & 7;
    wt[(kt * 4 + ks) * 2048 + col * 8 + e] = f2bf(kv[t]);
}

// ---- kernel 3: 3-deep pipelined implicit GEMM ----
// grid 729 (BM=64), 4 waves, wave tile 64x64, BK=32, 36 phases.
// A: LDS 3-deep 3x4KB row-major [row][slot^f(row)][8] (XOR on global source,
//    lane-linear gload_lds dest); staged 1 gload_lds/thread.
// B: registers 3-deep (3 named sets x 4 frags), 4 global_load_dwordx4/thread
//    from pre-tiled wt; issued BEFORE the MFMA cluster (writes set (k+2)%3,
//    no conflict with set k%3 being read -> issue hides under MFMA).
// Uniform 5 vmem/thread/phase; steady counted vmcnt(6); >=2-phase load cover.
__global__ __launch_bounds__(256, 3) void spconv_gemm(const u16* __restrict__ xb,
                                                      const u16* __restrict__ wt,
                                                      const float* __restrict__ bias,
                                                      float* __restrict__ out) {
    __shared__ __align__(16) u16 As[3][64 * 32];   // 3 x 4 KB

    const int t    = threadIdx.x;
    const int lane = t & 63;
    const int wid  = t >> 6;

    // bijective XCD swizzle (nwg=729 -> m204 formula)
    const int nwg = gridDim.x;
    const int q = nwg >> 3, r = nwg & 7;
    const int xcd = blockIdx.x & 7, inner = blockIdx.x >> 3;
    const int wg = (xcd < r ? xcd * (q + 1) : r * (q + 1) + (xcd - r) * q) + inner;
    const int m0 = wg * 64;

    // A staging: cell t = (row=t>>2, sd=t&3); src chunk = sd ^ f(row),
    // f(row) = (row&3)^((row>>2)&3). 4 lanes/row -> 64B sectors.
    const int arow = t >> 2;
    const int kco  = ((t & 3) ^ (arow & 3) ^ ((arow >> 2) & 3)) * 8;
    const u16* a_base;
    {
        int mg  = m0 + arow;
        int bb  = mg / (OH_ * OW_);
        int rem = mg % (OH_ * OW_);
        int ii  = rem / OW_;
        int jj  = rem % OW_;
        a_base = xb + ((bb * H_ + ii) * W_ + jj) * C_;
    }

    const int ks   = lane >> 4;
    const int r16  = lane & 15;
    const int cidx = ks ^ (r16 & 3) ^ ((r16 >> 2) & 3);   // mf-invariant

    // B: per-lane base into pre-tiled wt (bytes); per tile advance 16384B.
    // lane l: chunk ks = l>>4 (plane *4096B), col = wid*64 + nf*16 + r16
    const char* bptr = (const char*)wt + ks * 4096 + (wid * 64 + r16) * 16;

    f32x4 acc[4][4];
    const f32x4 zz = {0.f, 0.f, 0.f, 0.f};
#pragma unroll
    for (int i = 0; i < 4; ++i)
#pragma unroll
        for (int j = 0; j < 4; ++j) acc[i][j] = zz;

    bf16x8 bs[3][4];   // 3-deep B regsets (indices constant after unroll)

#define LOADB(dst, base, imm) \
    asm volatile("global_load_dwordx4 %0, %1, off offset:" imm \
                 : "=v"(dst) : "v"(base))

#define ISSUE_B(si) do {                                                    \
    LOADB(bs[si][0], bptr, "0");   LOADB(bs[si][1], bptr, "256");           \
    LOADB(bs[si][2], bptr, "512"); LOADB(bs[si][3], bptr, "768");           \
    bptr += 16384;                                                          \
} while (0)

#define ISSUE_A(kn, bi) do {                                                \
    int g_  = (kn) >> 2;                                                    \
    int di_ = (g_ * 11) >> 5;                                               \
    int dj_ = g_ - 3 * di_;                                                 \
    int aoff_ = (di_ * W_ + dj_) * C_ + ((kn) & 3) * 32 + kco;              \
    gload16(a_base + aoff_, &As[bi][t * 8]);                                \
} while (0)

#define COMPUTE(bi, si) do {                                                \
    bf16x8 a0_ = *(const bf16x8*)(&As[bi][(r16) * 32 + cidx * 8]);          \
    bf16x8 a1_ = *(const bf16x8*)(&As[bi][(16 + r16) * 32 + cidx * 8]);     \
    bf16x8 a2_ = *(const bf16x8*)(&As[bi][(32 + r16) * 32 + cidx * 8]);     \
    bf16x8 a3_ = *(const bf16x8*)(&As[bi][(48 + r16) * 32 + cidx * 8]);     \
    _Pragma("unroll")                                                       \
    for (int nf = 0; nf < 4; ++nf) {                                        \
        acc[0][nf] = __builtin_amdgcn_mfma_f32_16x16x32_bf16(a0_, bs[si][nf], acc[0][nf], 0, 0, 0); \
        acc[1][nf] = __builtin_amdgcn_mfma_f32_16x16x32_bf16(a1_, bs[si][nf], acc[1][nf], 0, 0, 0); \
        acc[2][nf] = __builtin_amdgcn_mfma_f32_16x16x32_bf16(a2_, bs[si][nf], acc[2][nf], 0, 0, 0); \
        acc[3][nf] = __builtin_amdgcn_mfma_f32_16x16x32_bf16(a3_, bs[si][nf], acc[3][nf], 0, 0, 0); \
    }                                                                       \
} while (0)

#define WAITVM(n) asm volatile("s_waitcnt vmcnt(" #n ")" ::: "memory")
#define BAR() do { __builtin_amdgcn_s_barrier();                            \
                   asm volatile("" ::: "memory"); } while (0)

    // prologue: [B0, A0, B1, A1, A2] -> 11 vmem in flight
    ISSUE_B(0);
    ISSUE_A(0, 0);
    ISSUE_B(1);
    ISSUE_A(1, 1);
    ISSUE_A(2, 2);

    // phases 0..32 (full): wait(6) drains tile-k A+B; issue B(k+2), A(k+3)
#pragma unroll
    for (int k = 0; k < 33; ++k) {
        WAITVM(6); BAR();
        ISSUE_B((k + 2) % 3);         // constant after unroll
        COMPUTE(k % 3, k % 3);
        BAR();
        ISSUE_A(k + 3, k % 3);
    }
    // phase 33: issue B35 only
    WAITVM(6); BAR();
    ISSUE_B(2);
    COMPUTE(0, 0);
    BAR();
    // phase 34
    WAITVM(5); BAR();
    COMPUTE(1, 1);
    // phase 35
    WAITVM(0); BAR();
    COMPUTE(2, 2);

#undef LOADB
#undef ISSUE_B
#undef ISSUE_A
#undef COMPUTE
#undef WAITVM
#undef BAR

    // epilogue: C/D layout col = lane&15, row = (lane>>4)*4 + reg (m89-verified)
    const int rgrp = lane >> 4;
#pragma unroll
    for (int nf = 0; nf < 4; ++nf) {
        int col  = wid * 64 + nf * 16 + r16;
        float bv = bias[col];
#pragma unroll
        for (int mf = 0; mf < 4; ++mf) {
#pragma unroll
            for (int rr = 0; rr < 4; ++rr) {
                int row = m0 + mf * 16 + rgrp * 4 + rr;
                float v = acc[mf][nf][rr] + bv;
                out[row * NF_ + col] = fmaxf(v, 0.f);
            }
        }
    }
}

extern "C" void kernel_launch(void* const* d_in, const int* in_sizes, int n_in,
                              void* d_out, int out_size, void* d_ws, size_t ws_size,
                              hipStream_t stream) {
    const float* x    = (const float*)d_in[0];
    const float* kv   = (const float*)d_in[1];
    const float* bias = (const float*)d_in[2];
    const int*   idx  = (const int*)d_in[3];
    float* out = (float*)d_out;

    u16* xb  = (u16*)d_ws;
    u16* wtp = (u16*)((char*)d_ws + (size_t)XB_ELEMS * 2);

    cvt_x_kernel<<<XB_ELEMS / (256 * 8), 256, 0, stream>>>(x, xb, wtp);
    scatter_kernel<<<(NNZ_ + 255) / 256, 256, 0, stream>>>(kv, idx, wtp);
    spconv_gemm<<<M_ / 64, 256, 0, stream>>>(xb, wtp, bias, out);
}